// Round 5
// baseline (1803.944 us; speedup 1.0000x reference)
//
#include <hip/hip_runtime.h>
#include <hip/hip_cooperative_groups.h>

namespace cg = cooperative_groups;

#define NN 10000
#define NN_P 10048          // padded rows for guard-free GEMM loads
#define NE 320000
#define F  128
#define BLK  256

struct Params {
    const float* ef;
    const int* src; const int* dst;
    const float* W1; const float* b1;
    const float* W2; const float* b2;
    const float* W3; const float* b3;
    const float* W4; const float* b4;
    const float* W5; const float* b5;
    float* out;
    int* deg; int* offs; int* cursor; int* csr; int* csrc;
    float* invdeg;
    float* nodeA; float* nodeB; float* z;
};

// ================= CSR phases (grid-stride; work independent of grid size) ===========
__device__ __forceinline__ void csr_zero(int* deg) {
    int gs = gridDim.x * BLK;
    for (int i = blockIdx.x * BLK + threadIdx.x; i < NN; i += gs) deg[i] = 0;
}
__device__ __forceinline__ void csr_count(const int* dst, int* deg) {
    int gs = gridDim.x * BLK;
    for (int e = blockIdx.x * BLK + threadIdx.x; e < NE; e += gs) atomicAdd(&deg[dst[e]], 1);
}
__device__ __forceinline__ void csr_scan(const int* deg, int* offs, int* cursor,
                                         float* invdeg, int* sscan) {
    if (blockIdx.x != 0) return;
    int t = threadIdx.x;
    int lo = t * 40, hi = min(lo + 40, NN);
    int sum = 0;
    for (int i = lo; i < hi; ++i) sum += deg[i];
    sscan[t] = sum;
    __syncthreads();
    for (int off = 1; off < 256; off <<= 1) {
        int v = (t >= off) ? sscan[t - off] : 0;
        __syncthreads();
        sscan[t] += v;
        __syncthreads();
    }
    int base = sscan[t] - sum;
    for (int i = lo; i < hi; ++i) {
        int c = deg[i];
        offs[i] = base;
        cursor[i] = base;
        invdeg[i] = 1.0f / (float)c;
        base += c;
    }
    if (t == 0) offs[NN] = NE;
}
__device__ __forceinline__ void csr_fill(const int* dst, const int* src, int* cursor,
                                         int* csr, int* csrc) {
    int gs = gridDim.x * BLK;
    for (int e = blockIdx.x * BLK + threadIdx.x; e < NE; e += gs) {
        int p = atomicAdd(&cursor[dst[e]], 1);
        csr[p] = e;
        csrc[p] = src[e];
    }
}

// ================= gather phase =================
// Out[n] = scale[n] * sum_{i in seg(n)} op(T[idx[i]])
//   RELU: relu(0.5*(v + T[n]) + bias)   (fused prev-layer edge compute)
// One node per block-iteration: 256 threads = 8 edge slots x 32 float4 chunks.
template <bool RELU>
__device__ void gather_phase(const float4* __restrict__ T, const int* __restrict__ idx,
                             const int* __restrict__ offs, const float4* __restrict__ bias4,
                             const float* __restrict__ scale, float4* __restrict__ Out,
                             int* sidx, float4 (*red)[32]) {
    int t = threadIdx.x;
    int slot = t >> 5, ch = t & 31;
    for (int n = blockIdx.x; n < NN; n += gridDim.x) {
        int a = offs[n], bnd = offs[n + 1];
        int deg = bnd - a;
        float4 zn = make_float4(0.f, 0.f, 0.f, 0.f);
        float4 b4 = make_float4(0.f, 0.f, 0.f, 0.f);
        if (RELU) { zn = T[(size_t)n * 32 + ch]; b4 = bias4[ch]; }
        float ax = 0.f, ay = 0.f, az = 0.f, aw = 0.f;

        for (int base = 0; base < deg; base += 64) {
            int cnt = min(64, deg - base);
            __syncthreads();                 // protects sidx AND red reuse
            if (t < cnt) sidx[t] = idx[a + base + t];
            __syncthreads();
            int j = slot;
            for (; j + 8 < cnt; j += 16) {
                int s0 = sidx[j], s1 = sidx[j + 8];
                float4 v0 = T[(size_t)s0 * 32 + ch];
                float4 v1 = T[(size_t)s1 * 32 + ch];
                if (RELU) {
                    ax += fmaxf(0.5f * (v0.x + zn.x) + b4.x, 0.f) + fmaxf(0.5f * (v1.x + zn.x) + b4.x, 0.f);
                    ay += fmaxf(0.5f * (v0.y + zn.y) + b4.y, 0.f) + fmaxf(0.5f * (v1.y + zn.y) + b4.y, 0.f);
                    az += fmaxf(0.5f * (v0.z + zn.z) + b4.z, 0.f) + fmaxf(0.5f * (v1.z + zn.z) + b4.z, 0.f);
                    aw += fmaxf(0.5f * (v0.w + zn.w) + b4.w, 0.f) + fmaxf(0.5f * (v1.w + zn.w) + b4.w, 0.f);
                } else {
                    ax += v0.x + v1.x; ay += v0.y + v1.y;
                    az += v0.z + v1.z; aw += v0.w + v1.w;
                }
            }
            if (j < cnt) {
                int s0 = sidx[j];
                float4 v0 = T[(size_t)s0 * 32 + ch];
                if (RELU) {
                    ax += fmaxf(0.5f * (v0.x + zn.x) + b4.x, 0.f);
                    ay += fmaxf(0.5f * (v0.y + zn.y) + b4.y, 0.f);
                    az += fmaxf(0.5f * (v0.z + zn.z) + b4.z, 0.f);
                    aw += fmaxf(0.5f * (v0.w + zn.w) + b4.w, 0.f);
                } else {
                    ax += v0.x; ay += v0.y; az += v0.z; aw += v0.w;
                }
            }
        }

        red[slot][ch] = make_float4(ax, ay, az, aw);
        __syncthreads();
        if (t < 32) {
            float4 r = red[0][t];
            #pragma unroll
            for (int s = 1; s < 8; ++s) {
                float4 q = red[s][t];
                r.x += q.x; r.y += q.y; r.z += q.z; r.w += q.w;
            }
            float sc = scale ? scale[n] : 1.0f;
            r.x *= sc; r.y *= sc; r.z *= sc; r.w *= sc;
            Out[(size_t)n * 32 + t] = r;
        }
        // next iteration's loop-entry __syncthreads() protects red/sidx before overwrite
    }
}

// ================= node GEMM phase: Z = X @ W^T =================
template <int OUT>
__device__ void gemm_phase(const float* __restrict__ X, const float* __restrict__ Wm,
                           float* __restrict__ Z) {
    constexpr int COLT = OUT / 64;
    constexpr int NT = (NN_P / 32) * COLT;
    int tx = threadIdx.x & 15, ty = threadIdx.x >> 4;
    for (int tile = blockIdx.x; tile < NT; tile += gridDim.x) {
        int c0 = (tile % COLT) * 64 + tx * 4;
        int r0 = (tile / COLT) * 32 + ty * 2;
        float acc[2][4] = {};
#pragma unroll 8
        for (int k = 0; k < 128; k += 4) {
            float4 x0 = *reinterpret_cast<const float4*>(&X[(size_t)r0 * F + k]);
            float4 x1 = *reinterpret_cast<const float4*>(&X[(size_t)(r0 + 1) * F + k]);
            float4 w0 = *reinterpret_cast<const float4*>(&Wm[(size_t)(c0 + 0) * F + k]);
            float4 w1 = *reinterpret_cast<const float4*>(&Wm[(size_t)(c0 + 1) * F + k]);
            float4 w2 = *reinterpret_cast<const float4*>(&Wm[(size_t)(c0 + 2) * F + k]);
            float4 w3 = *reinterpret_cast<const float4*>(&Wm[(size_t)(c0 + 3) * F + k]);
            acc[0][0] += x0.x * w0.x + x0.y * w0.y + x0.z * w0.z + x0.w * w0.w;
            acc[0][1] += x0.x * w1.x + x0.y * w1.y + x0.z * w1.z + x0.w * w1.w;
            acc[0][2] += x0.x * w2.x + x0.y * w2.y + x0.z * w2.z + x0.w * w2.w;
            acc[0][3] += x0.x * w3.x + x0.y * w3.y + x0.z * w3.z + x0.w * w3.w;
            acc[1][0] += x1.x * w0.x + x1.y * w0.y + x1.z * w0.z + x1.w * w0.w;
            acc[1][1] += x1.x * w1.x + x1.y * w1.y + x1.z * w1.z + x1.w * w1.w;
            acc[1][2] += x1.x * w2.x + x1.y * w2.y + x1.z * w2.z + x1.w * w2.w;
            acc[1][3] += x1.x * w3.x + x1.y * w3.y + x1.z * w3.z + x1.w * w3.w;
        }
#pragma unroll
        for (int i = 0; i < 2; ++i) {
            if (r0 + i < NN) {
                float4 v = make_float4(acc[i][0], acc[i][1], acc[i][2], acc[i][3]);
                *reinterpret_cast<float4*>(&Z[(size_t)(r0 + i) * OUT + c0]) = v;
            }
        }
    }
}

// ================= final edge output =================
__device__ void edge_out_phase(const float4* __restrict__ z5, const float4* __restrict__ b5v,
                               const int* __restrict__ src, const int* __restrict__ dst,
                               float4* __restrict__ outp) {
    int gs = gridDim.x * BLK;
    for (int t = blockIdx.x * BLK + threadIdx.x; t < NE * 16; t += gs) {
        int e = t >> 4, ch = t & 15;
        float4 a = z5[(size_t)src[e] * 16 + ch];
        float4 b = z5[(size_t)dst[e] * 16 + ch];
        float4 c = b5v[ch];
        float4 r;
        r.x = 0.5f * (a.x + b.x) + c.x;
        r.y = 0.5f * (a.y + b.y) + c.y;
        r.z = 0.5f * (a.z + b.z) + c.z;
        r.w = 0.5f * (a.w + b.w) + c.w;
        outp[(size_t)e * 16 + ch] = r;
    }
}

// ================= cooperative all-in-one =================
__global__ __launch_bounds__(BLK, 2) void gcn_all(Params P) {
    cg::grid_group g = cg::this_grid();
    __shared__ int sidx[64];
    __shared__ float4 red[8][32];
    __shared__ int sscan[256];

    csr_zero(P.deg);                                   g.sync();
    csr_count(P.dst, P.deg);                           g.sync();
    csr_scan(P.deg, P.offs, P.cursor, P.invdeg, sscan); g.sync();
    csr_fill(P.dst, P.src, P.cursor, P.csr, P.csrc);   g.sync();

    const float4* ef4 = (const float4*)P.ef;
    float4* nodeA4 = (float4*)P.nodeA;
    float4* nodeB4 = (float4*)P.nodeB;
    const float4* z4 = (const float4*)P.z;

    gather_phase<false>(ef4, P.csr, P.offs, nullptr, P.invdeg, nodeA4, sidx, red);
    g.sync();
    gather_phase<false>((const float4*)P.nodeA, P.csrc, P.offs, nullptr, nullptr, nodeB4, sidx, red);
    g.sync();
    gemm_phase<128>(P.nodeB, P.W1, P.z);
    g.sync();

    const float* Wl[3] = {P.W2, P.W3, P.W4};
    const float* bl[3] = {P.b1, P.b2, P.b3};
    for (int L = 0; L < 3; ++L) {
        gather_phase<true>(z4, P.csrc, P.offs, (const float4*)bl[L], P.invdeg, nodeA4, sidx, red);
        g.sync();
        gather_phase<false>((const float4*)P.nodeA, P.csrc, P.offs, nullptr, nullptr, nodeB4, sidx, red);
        g.sync();
        gemm_phase<128>(P.nodeB, Wl[L], P.z);
        g.sync();
    }

    gather_phase<true>(z4, P.csrc, P.offs, (const float4*)P.b4, P.invdeg, nodeA4, sidx, red);
    g.sync();
    gather_phase<false>((const float4*)P.nodeA, P.csrc, P.offs, nullptr, nullptr, nodeB4, sidx, red);
    g.sync();
    gemm_phase<64>(P.nodeB, P.W5, P.z);
    g.sync();

    edge_out_phase(z4, (const float4*)P.b5, P.src, P.dst, (float4*)P.out);
}

// ================= fallback wrappers (identical math, separate launches) =============
__global__ __launch_bounds__(BLK) void k_csr_zero(Params P)  { csr_zero(P.deg); }
__global__ __launch_bounds__(BLK) void k_csr_count(Params P) { csr_count(P.dst, P.deg); }
__global__ __launch_bounds__(BLK) void k_csr_scan(Params P)  {
    __shared__ int sscan[256];
    csr_scan(P.deg, P.offs, P.cursor, P.invdeg, sscan);
}
__global__ __launch_bounds__(BLK) void k_csr_fill(Params P)  { csr_fill(P.dst, P.src, P.cursor, P.csr, P.csrc); }
template <bool RELU>
__global__ __launch_bounds__(BLK) void k_gather(const float4* T, const int* idx,
                                                const int* offs, const float4* bias4,
                                                const float* scale, float4* Out) {
    __shared__ int sidx[64];
    __shared__ float4 red[8][32];
    gather_phase<RELU>(T, idx, offs, bias4, scale, Out, sidx, red);
}
template <int OUT>
__global__ __launch_bounds__(BLK) void k_gemm(const float* X, const float* Wm, float* Z) {
    gemm_phase<OUT>(X, Wm, Z);
}
__global__ __launch_bounds__(BLK) void k_edge_out(Params P) {
    edge_out_phase((const float4*)P.z, (const float4*)P.b5, P.src, P.dst, (float4*)P.out);
}

extern "C" void kernel_launch(void* const* d_in, const int* in_sizes, int n_in,
                              void* d_out, int out_size, void* d_ws, size_t ws_size,
                              hipStream_t stream) {
    char* p = (char*)d_ws;
    auto alloc = [&](size_t bytes) {
        char* r = p;
        p += (bytes + 255) & ~(size_t)255;
        return r;
    };
    Params prm;
    prm.ef  = (const float*)d_in[0];
    prm.src = (const int*)d_in[1];
    prm.dst = (const int*)d_in[2];
    prm.W1 = (const float*)d_in[3];  prm.b1 = (const float*)d_in[4];
    prm.W2 = (const float*)d_in[5];  prm.b2 = (const float*)d_in[6];
    prm.W3 = (const float*)d_in[7];  prm.b3 = (const float*)d_in[8];
    prm.W4 = (const float*)d_in[9];  prm.b4 = (const float*)d_in[10];
    prm.W5 = (const float*)d_in[11]; prm.b5 = (const float*)d_in[12];
    prm.out = (float*)d_out;
    prm.deg    = (int*)alloc(NN * 4);
    prm.offs   = (int*)alloc((NN + 1) * 4);
    prm.cursor = (int*)alloc(NN * 4);
    prm.csr    = (int*)alloc((size_t)NE * 4);
    prm.csrc   = (int*)alloc((size_t)NE * 4);
    prm.invdeg = (float*)alloc(NN * 4);
    prm.nodeA  = (float*)alloc((size_t)NN_P * F * 4);
    prm.nodeB  = (float*)alloc((size_t)NN_P * F * 4);
    prm.z      = (float*)alloc((size_t)NN_P * F * 4);

    // ---- co-residency-safe cooperative launch, with checked fallback ----
    int occ = 0;
    hipError_t qerr = hipOccupancyMaxActiveBlocksPerMultiprocessor(&occ, gcn_all, BLK, 0);
    bool coop_ok = false;
    if (qerr == hipSuccess && occ >= 1) {
        int grid = occ * 256;            // 256 CUs on MI355X
        if (grid > 1024) grid = 1024;
        void* args[] = { &prm };
        hipError_t lerr = hipLaunchCooperativeKernel((const void*)gcn_all, dim3(grid),
                                                     dim3(BLK), args, 0, stream);
        coop_ok = (lerr == hipSuccess);
    }
    if (coop_ok) return;

    // ---- fallback: identical phases as separate launches ----
    const float4* z4 = (const float4*)prm.z;
    float4* nodeA4 = (float4*)prm.nodeA;
    float4* nodeB4 = (float4*)prm.nodeB;

    k_csr_zero<<<64, BLK, 0, stream>>>(prm);
    k_csr_count<<<512, BLK, 0, stream>>>(prm);
    k_csr_scan<<<1, BLK, 0, stream>>>(prm);
    k_csr_fill<<<512, BLK, 0, stream>>>(prm);

    k_gather<false><<<1024, BLK, 0, stream>>>((const float4*)prm.ef, prm.csr, prm.offs, nullptr, prm.invdeg, nodeA4);
    k_gather<false><<<1024, BLK, 0, stream>>>((const float4*)prm.nodeA, prm.csrc, prm.offs, nullptr, nullptr, nodeB4);
    k_gemm<128><<<628, BLK, 0, stream>>>(prm.nodeB, prm.W1, prm.z);

    const float* Wl[3] = {prm.W2, prm.W3, prm.W4};
    const float* bl[3] = {prm.b1, prm.b2, prm.b3};
    for (int L = 0; L < 3; ++L) {
        k_gather<true><<<1024, BLK, 0, stream>>>(z4, prm.csrc, prm.offs, (const float4*)bl[L], prm.invdeg, nodeA4);
        k_gather<false><<<1024, BLK, 0, stream>>>((const float4*)prm.nodeA, prm.csrc, prm.offs, nullptr, nullptr, nodeB4);
        k_gemm<128><<<628, BLK, 0, stream>>>(prm.nodeB, Wl[L], prm.z);
    }

    k_gather<true><<<1024, BLK, 0, stream>>>(z4, prm.csrc, prm.offs, (const float4*)prm.b4, prm.invdeg, nodeA4);
    k_gather<false><<<1024, BLK, 0, stream>>>((const float4*)prm.nodeA, prm.csrc, prm.offs, nullptr, nullptr, nodeB4);
    k_gemm<64><<<314, BLK, 0, stream>>>(prm.nodeB, prm.W5, prm.z);

    k_edge_out<<<2048, BLK, 0, stream>>>(prm);
}

// Round 6
// 419.097 us; speedup vs baseline: 4.3044x; 4.3044x over previous
//
#include <hip/hip_runtime.h>

#define NN 10000
#define NE 320000
#define F  128
#define BLK 256

// ---------- CSR build ----------
__global__ void count_kernel(const int* __restrict__ dst, int* __restrict__ deg) {
    int e = blockIdx.x * 256 + threadIdx.x;
    if (e < NE) atomicAdd(&deg[dst[e]], 1);
}

__global__ __launch_bounds__(1024) void scan_kernel(const int* __restrict__ deg,
                                                    int* __restrict__ offs,
                                                    int* __restrict__ cursor,
                                                    float* __restrict__ invdeg) {
    __shared__ int s[1024];
    int t = threadIdx.x;
    int lo = t * 10;
    int hi = min(lo + 10, NN);
    int sum = 0;
    for (int i = lo; i < hi; ++i) sum += deg[i];
    s[t] = sum;
    __syncthreads();
    for (int off = 1; off < 1024; off <<= 1) {
        int v = (t >= off) ? s[t - off] : 0;
        __syncthreads();
        s[t] += v;
        __syncthreads();
    }
    int base = s[t] - sum;  // exclusive prefix
    for (int i = lo; i < hi; ++i) {
        int c = deg[i];
        offs[i]   = base;
        cursor[i] = base;
        invdeg[i] = 1.0f / (float)c;  // every node has >=1 in-edge
        base += c;
    }
    if (t == 0) offs[NN] = NE;
}

// fill CSR; also pre-resolve csrc[p] = src[e]
__global__ void fill_kernel(const int* __restrict__ dst, const int* __restrict__ src,
                            int* __restrict__ cursor, int* __restrict__ csr,
                            int* __restrict__ csrc) {
    int e = blockIdx.x * 256 + threadIdx.x;
    if (e < NE) {
        int p = atomicAdd(&cursor[dst[e]], 1);
        csr[p] = e;
        csrc[p] = src[e];
    }
}

// ---------- gather (mean / fused-relu-edge variants) ----------
// Out[n] = invdeg[n] * sum_{i in seg(n)} op(T[idx[i]])
//   MODE 0: op(v) = v                                  (layer-1 seg-mean of edge_feats)
//   MODE 1: op(v) = relu(0.5*(v + T[n]) + bias)        (fused prev-layer edge compute)
// block = 256 threads = 2 nodes x 4 edge-slots x 32 float4 chunks; 4 rows in flight/thread
template <int MODE>
__global__ __launch_bounds__(256) void gather_k(const float4* __restrict__ T,
                                                const int* __restrict__ idx,
                                                const int* __restrict__ offs,
                                                const float4* __restrict__ bias4,
                                                const float* __restrict__ invdeg,
                                                float4* __restrict__ Out) {
    __shared__ float4 red[8][32];
    int t  = threadIdx.x;
    int ns = t >> 7;          // node slot 0..1
    int es = (t >> 5) & 3;    // edge slot 0..3
    int ch = t & 31;          // float4 chunk 0..31
    int n  = blockIdx.x * 2 + ns;
    int a = offs[n], bnd = offs[n + 1];

    float4 zn = make_float4(0.f, 0.f, 0.f, 0.f);
    float4 bb = make_float4(0.f, 0.f, 0.f, 0.f);
    if (MODE == 1) { zn = T[(size_t)n * 32 + ch]; bb = bias4[ch]; }
    float ax = 0.f, ay = 0.f, az = 0.f, aw = 0.f;

    int i = a + es;
    for (; i + 12 < bnd; i += 16) {       // 4 rows in flight per thread
        int s0 = idx[i], s1 = idx[i + 4], s2 = idx[i + 8], s3 = idx[i + 12];
        float4 v0 = T[(size_t)s0 * 32 + ch];
        float4 v1 = T[(size_t)s1 * 32 + ch];
        float4 v2 = T[(size_t)s2 * 32 + ch];
        float4 v3 = T[(size_t)s3 * 32 + ch];
        if (MODE == 1) {
            ax += fmaxf(0.5f * (v0.x + zn.x) + bb.x, 0.f) + fmaxf(0.5f * (v1.x + zn.x) + bb.x, 0.f)
                + fmaxf(0.5f * (v2.x + zn.x) + bb.x, 0.f) + fmaxf(0.5f * (v3.x + zn.x) + bb.x, 0.f);
            ay += fmaxf(0.5f * (v0.y + zn.y) + bb.y, 0.f) + fmaxf(0.5f * (v1.y + zn.y) + bb.y, 0.f)
                + fmaxf(0.5f * (v2.y + zn.y) + bb.y, 0.f) + fmaxf(0.5f * (v3.y + zn.y) + bb.y, 0.f);
            az += fmaxf(0.5f * (v0.z + zn.z) + bb.z, 0.f) + fmaxf(0.5f * (v1.z + zn.z) + bb.z, 0.f)
                + fmaxf(0.5f * (v2.z + zn.z) + bb.z, 0.f) + fmaxf(0.5f * (v3.z + zn.z) + bb.z, 0.f);
            aw += fmaxf(0.5f * (v0.w + zn.w) + bb.w, 0.f) + fmaxf(0.5f * (v1.w + zn.w) + bb.w, 0.f)
                + fmaxf(0.5f * (v2.w + zn.w) + bb.w, 0.f) + fmaxf(0.5f * (v3.w + zn.w) + bb.w, 0.f);
        } else {
            ax += v0.x + v1.x + v2.x + v3.x;
            ay += v0.y + v1.y + v2.y + v3.y;
            az += v0.z + v1.z + v2.z + v3.z;
            aw += v0.w + v1.w + v2.w + v3.w;
        }
    }
    for (; i < bnd; i += 4) {
        int s0 = idx[i];
        float4 v0 = T[(size_t)s0 * 32 + ch];
        if (MODE == 1) {
            ax += fmaxf(0.5f * (v0.x + zn.x) + bb.x, 0.f);
            ay += fmaxf(0.5f * (v0.y + zn.y) + bb.y, 0.f);
            az += fmaxf(0.5f * (v0.z + zn.z) + bb.z, 0.f);
            aw += fmaxf(0.5f * (v0.w + zn.w) + bb.w, 0.f);
        } else {
            ax += v0.x; ay += v0.y; az += v0.z; aw += v0.w;
        }
    }

    red[t >> 5][ch] = make_float4(ax, ay, az, aw);
    __syncthreads();
    if (t < 64) {
        int ns2 = t >> 5, c2 = t & 31;
        float4 r0 = red[ns2 * 4 + 0][c2];
        float4 r1 = red[ns2 * 4 + 1][c2];
        float4 r2 = red[ns2 * 4 + 2][c2];
        float4 r3 = red[ns2 * 4 + 3][c2];
        int n2 = blockIdx.x * 2 + ns2;
        float sc = invdeg[n2];
        float4 r;
        r.x = (r0.x + r1.x + r2.x + r3.x) * sc;
        r.y = (r0.y + r1.y + r2.y + r3.y) * sc;
        r.z = (r0.z + r1.z + r2.z + r3.z) * sc;
        r.w = (r0.w + r1.w + r2.w + r3.w) * sc;
        Out[(size_t)n2 * 32 + c2] = r;
    }
}

// ---------- fused sum-gather + per-node matvec ----------
// x[n] = sum_{i in seg(n)} T[idx[i]]   (2 nodes per block, reduced into LDS)
// Z[n] = W @ x[n]                      (threads 0..OUT-1, W rows float4 from L2)
template <int OUT>
__global__ __launch_bounds__(256) void sum_gemm_k(const float4* __restrict__ T,
                                                  const int* __restrict__ idx,
                                                  const int* __restrict__ offs,
                                                  const float* __restrict__ Wm,
                                                  float* __restrict__ Z) {
    __shared__ float4 red[8][32];
    __shared__ float  xs[2][128];
    int t  = threadIdx.x;
    int ns = t >> 7;
    int es = (t >> 5) & 3;
    int ch = t & 31;
    int n  = blockIdx.x * 2 + ns;
    int a = offs[n], bnd = offs[n + 1];

    float ax = 0.f, ay = 0.f, az = 0.f, aw = 0.f;
    int i = a + es;
    for (; i + 12 < bnd; i += 16) {
        int s0 = idx[i], s1 = idx[i + 4], s2 = idx[i + 8], s3 = idx[i + 12];
        float4 v0 = T[(size_t)s0 * 32 + ch];
        float4 v1 = T[(size_t)s1 * 32 + ch];
        float4 v2 = T[(size_t)s2 * 32 + ch];
        float4 v3 = T[(size_t)s3 * 32 + ch];
        ax += v0.x + v1.x + v2.x + v3.x;
        ay += v0.y + v1.y + v2.y + v3.y;
        az += v0.z + v1.z + v2.z + v3.z;
        aw += v0.w + v1.w + v2.w + v3.w;
    }
    for (; i < bnd; i += 4) {
        int s0 = idx[i];
        float4 v0 = T[(size_t)s0 * 32 + ch];
        ax += v0.x; ay += v0.y; az += v0.z; aw += v0.w;
    }

    red[t >> 5][ch] = make_float4(ax, ay, az, aw);
    __syncthreads();
    if (t < 64) {
        int ns2 = t >> 5, c2 = t & 31;
        float4 r0 = red[ns2 * 4 + 0][c2];
        float4 r1 = red[ns2 * 4 + 1][c2];
        float4 r2 = red[ns2 * 4 + 2][c2];
        float4 r3 = red[ns2 * 4 + 3][c2];
        float4 r;
        r.x = r0.x + r1.x + r2.x + r3.x;
        r.y = r0.y + r1.y + r2.y + r3.y;
        r.z = r0.z + r1.z + r2.z + r3.z;
        r.w = r0.w + r1.w + r2.w + r3.w;
        *reinterpret_cast<float4*>(&xs[ns2][c2 * 4]) = r;
    }
    __syncthreads();

    // matvec for both nodes: thread o in [0, OUT)
    if (t < OUT) {
        const float4* wrow = reinterpret_cast<const float4*>(&Wm[(size_t)t * 128]);
        float acc0 = 0.f, acc1 = 0.f;
#pragma unroll 8
        for (int k4 = 0; k4 < 32; ++k4) {
            float4 w  = wrow[k4];
            float4 x0 = *reinterpret_cast<const float4*>(&xs[0][k4 * 4]);
            float4 x1 = *reinterpret_cast<const float4*>(&xs[1][k4 * 4]);
            acc0 += w.x * x0.x + w.y * x0.y + w.z * x0.z + w.w * x0.w;
            acc1 += w.x * x1.x + w.y * x1.y + w.z * x1.z + w.w * x1.w;
        }
        Z[(size_t)(blockIdx.x * 2 + 0) * OUT + t] = acc0;
        Z[(size_t)(blockIdx.x * 2 + 1) * OUT + t] = acc1;
    }
}

// ---------- final edge output: out[e] = 0.5*(z5[src]+z5[dst]) + b5 (64 feats) ----------
__global__ __launch_bounds__(256) void edge_out(const float4* __restrict__ z5,
                                                const float4* __restrict__ b5v,
                                                const int* __restrict__ src,
                                                const int* __restrict__ dst,
                                                float4* __restrict__ outp) {
    int t = blockIdx.x * 256 + threadIdx.x;
    int e = t >> 4, ch = t & 15;
    if (e < NE) {
        float4 a = z5[(size_t)src[e] * 16 + ch];
        float4 b = z5[(size_t)dst[e] * 16 + ch];
        float4 c = b5v[ch];
        float4 r;
        r.x = 0.5f * (a.x + b.x) + c.x;
        r.y = 0.5f * (a.y + b.y) + c.y;
        r.z = 0.5f * (a.z + b.z) + c.z;
        r.w = 0.5f * (a.w + b.w) + c.w;
        outp[(size_t)e * 16 + ch] = r;
    }
}

extern "C" void kernel_launch(void* const* d_in, const int* in_sizes, int n_in,
                              void* d_out, int out_size, void* d_ws, size_t ws_size,
                              hipStream_t stream) {
    const float* ef  = (const float*)d_in[0];
    const int*   src = (const int*)d_in[1];
    const int*   dst = (const int*)d_in[2];
    const float* W1 = (const float*)d_in[3];  const float* b1 = (const float*)d_in[4];
    const float* W2 = (const float*)d_in[5];  const float* b2 = (const float*)d_in[6];
    const float* W3 = (const float*)d_in[7];  const float* b3 = (const float*)d_in[8];
    const float* W4 = (const float*)d_in[9];  const float* b4 = (const float*)d_in[10];
    const float* W5 = (const float*)d_in[11]; const float* b5 = (const float*)d_in[12];
    float* out = (float*)d_out;

    char* p = (char*)d_ws;
    auto alloc = [&](size_t bytes) {
        char* r = p;
        p += (bytes + 255) & ~(size_t)255;
        return r;
    };
    int*   deg    = (int*)alloc(NN * 4);
    int*   offs   = (int*)alloc((NN + 1) * 4);
    int*   cursor = (int*)alloc(NN * 4);
    int*   csr    = (int*)alloc((size_t)NE * 4);
    int*   csrc   = (int*)alloc((size_t)NE * 4);
    float* invdeg = (float*)alloc(NN * 4);
    float* nodeA  = (float*)alloc((size_t)NN * F * 4);
    float* z      = (float*)alloc((size_t)NN * F * 4);

    // CSR build (4 dispatches)
    hipMemsetAsync(deg, 0, NN * 4, stream);
    count_kernel<<<(NE + 255) / 256, 256, 0, stream>>>(dst, deg);
    scan_kernel<<<1, 1024, 0, stream>>>(deg, offs, cursor, invdeg);
    fill_kernel<<<(NE + 255) / 256, 256, 0, stream>>>(dst, src, cursor, csr, csrc);

    const int GG = NN / 2;                 // 5000 blocks, 2 nodes each
    const float4* z4 = (const float4*)z;
    float4* nodeA4 = (float4*)nodeA;

    // ---- layer 1 ----
    gather_k<0><<<GG, BLK, 0, stream>>>((const float4*)ef, csr, offs, nullptr, invdeg, nodeA4);
    sum_gemm_k<128><<<GG, BLK, 0, stream>>>((const float4*)nodeA, csrc, offs, W1, z);

    // ---- layers 2..4 (prev layer's edge compute fused into the relu gather) ----
    const float* Wl[3] = {W2, W3, W4};
    const float* bl[3] = {b1, b2, b3};
    for (int L = 0; L < 3; ++L) {
        gather_k<1><<<GG, BLK, 0, stream>>>(z4, csrc, offs, (const float4*)bl[L], invdeg, nodeA4);
        sum_gemm_k<128><<<GG, BLK, 0, stream>>>((const float4*)nodeA, csrc, offs, Wl[L], z);
    }

    // ---- layer 5 ----
    gather_k<1><<<GG, BLK, 0, stream>>>(z4, csrc, offs, (const float4*)b4, invdeg, nodeA4);
    sum_gemm_k<64><<<GG, BLK, 0, stream>>>((const float4*)nodeA, csrc, offs, W5, z);

    // ---- final per-edge output (82 MB write) ----
    edge_out<<<(NE * 16 + 255) / 256, BLK, 0, stream>>>(z4, (const float4*)b5, src, dst, (float4*)out);
}